// Round 19
// baseline (130.757 us; speedup 1.0000x reference)
//
#include <hip/hip_runtime.h>
#include <math.h>

#define BB 256
#define SS 64
#define DIMM 1024
#define NHH 8
#define DHH 128

typedef short bf16x8 __attribute__((ext_vector_type(8)));
typedef float f32x4 __attribute__((ext_vector_type(4)));

// HW packed f32x2 -> bf16x2 (RNE). No builtin on gfx950; T12/m240-verified mnemonic.
__device__ __forceinline__ unsigned cvtpk(float lo, float hi) {
    unsigned r;
    asm("v_cvt_pk_bf16_f32 %0, %1, %2" : "=v"(r) : "v"(lo), "v"(hi));
    return r;
}
__device__ __forceinline__ unsigned pk2(float lo, float hi) { return cvtpk(lo, hi); }
__device__ __forceinline__ unsigned short f2bh(float x) {
    return (unsigned short)(cvtpk(x, 0.0f) & 0xFFFFu);
}
__device__ __forceinline__ float bf2f(unsigned short b) {
    union { unsigned u; float f; } x{((unsigned)b) << 16};
    return x.f;
}
// split a,b into hi-bf16 pair and residual-lo-bf16 pair (packed words)
__device__ __forceinline__ void split2(float a, float b, unsigned& hi, unsigned& lo) {
    hi = cvtpk(a, b);
    const float ha = __uint_as_float(hi << 16);
    const float hb = __uint_as_float(hi & 0xFFFF0000u);
    lo = cvtpk(a - ha, b - hb);
}
__device__ __forceinline__ float logsigf(float x) {
    return fminf(x, 0.0f) - log1pf(__expf(-fabsf(x)));
}

// ---------------------------------------------------------------------------
// Kernel 1a (v6): gate GEMM partials via global_load_lds async staging.
// grid = 1024 (b=bid&255, ksl=bid>>8 in [0,4)); K-slice = 768, 6 steps of 128.
// X staged f32 straight to LDS (8 async 16B-wide issues/wave, no VGPR
// round-trip); both-sides XOR swizzle (linear LDS dest + inverse-swizzled
// global source + swizzled ds_read) kills the 16-way column-read conflict.
// f32->bf16 conversion at MFMA-consume (cvt_pk, same RNE as before).
// partials layout: [ksl=4][b][s][16]
// ---------------------------------------------------------------------------
__global__ __launch_bounds__(256) void k_gate_mfma(
    const float* __restrict__ q, const float* __restrict__ k, const float* __restrict__ v,
    const float* __restrict__ igw, const float* __restrict__ fgw,
    float* __restrict__ part)
{
    __shared__ __attribute__((aligned(16))) float Xf[64 * 128];  // linear; holds swizzled rows
    __shared__ float Wf[16 * 132];                               // f32, padded
    const int b = blockIdx.x & 255;
    const int ksl = blockIdx.x >> 8;          // 0..3
    const int t = threadIdx.x;
    const int w = t >> 6, l = t & 63, c = l & 15, g = l >> 4;

    f32x4 acc;
    acc[0] = 0.f; acc[1] = 0.f; acc[2] = 0.f; acc[3] = 0.f;
    union bfu { unsigned u[4]; bf16x8 v; };

    for (int step = 0; step < 6; ++step) {
        const int kc = ksl * 6 + step;            // 128-col chunk 0..23
        const int tensor = kc >> 3;
        const float* src = (tensor == 0) ? q : (tensor == 1) ? k : v;
        const int colbase = (kc & 7) * 128;

        // ---- async X stage: wave w covers rows 16w..16w+15, 2 rows/issue ----
        {
            const int row_in = l >> 5;            // 0/1 within the 2-row chunk
            const unsigned wr = (unsigned)((l & 31) * 16);  // linear within-row dest byte
            #pragma unroll
            for (int i = 0; i < 8; ++i) {
                const int row = 16 * w + 2 * i + row_in;
                const unsigned sw = (unsigned)((row & 7) << 4);
                const char* gsrc = reinterpret_cast<const char*>(
                    src + (size_t)(b * 64 + row) * 1024 + colbase) + (wr ^ sw);
                float* ldst = Xf + (16 * w + 2 * i) * 128;    // wave-uniform base
                __builtin_amdgcn_global_load_lds(
                    (const __attribute__((address_space(1))) void*)gsrc,
                    (__attribute__((address_space(3))) void*)ldst, 16, 0, 0);
            }
        }
        // ---- W stage (f32 padded, tiny + L2-hot) ----
        {
            const int o = t >> 4, ws8 = t & 15;
            const float* wp = (o < 8 ? igw + o * 3072 : fgw + (o - 8) * 3072)
                              + ksl * 768 + step * 128 + 8 * ws8;
            const float4 a0 = *reinterpret_cast<const float4*>(wp);
            const float4 a1 = *reinterpret_cast<const float4*>(wp + 4);
            *reinterpret_cast<float4*>(&Wf[o * 132 + 8 * ws8]) = a0;
            *reinterpret_cast<float4*>(&Wf[o * 132 + 8 * ws8 + 4]) = a1;
        }
        __syncthreads();   // drains vmcnt (incl. global_load_lds) before reads

        // ---- MFMA: K=128 -> 4 sub-K; convert at consume ----
        const int R = 16 * w + c;
        const unsigned sw = (unsigned)((R & 7) << 4);
        const char* xbase = reinterpret_cast<const char*>(Xf) + R * 512;
        #pragma unroll
        for (int kk = 0; kk < 4; ++kk) {
            const unsigned F4 = (unsigned)((32 * kk + 8 * g) * 4);
            const float4 xa = *reinterpret_cast<const float4*>(xbase + (F4 ^ sw));
            const float4 xb = *reinterpret_cast<const float4*>(xbase + ((F4 + 16) ^ sw));
            const float4 wa = *reinterpret_cast<const float4*>(&Wf[c * 132 + 32 * kk + 8 * g]);
            const float4 wb = *reinterpret_cast<const float4*>(&Wf[c * 132 + 32 * kk + 8 * g + 4]);
            bfu af, bf;
            af.u[0] = pk2(xa.x, xa.y); af.u[1] = pk2(xa.z, xa.w);
            af.u[2] = pk2(xb.x, xb.y); af.u[3] = pk2(xb.z, xb.w);
            bf.u[0] = pk2(wa.x, wa.y); bf.u[1] = pk2(wa.z, wa.w);
            bf.u[2] = pk2(wb.x, wb.y); bf.u[3] = pk2(wb.z, wb.w);
            acc = __builtin_amdgcn_mfma_f32_16x16x32_bf16(af.v, bf.v, acc, 0, 0, 0);
        }
        __syncthreads();   // Xf dead before next step's staging
    }
    float* pb = part + (((size_t)ksl * 256 + b) * 64) * 16;
    #pragma unroll
    for (int reg = 0; reg < 4; ++reg) {
        const int s = 16 * w + 4 * g + reg;    // D: col=lane&15, row=4*(lane>>4)+reg
        pb[s * 16 + c] = acc[reg];
    }
}

// ---------------------------------------------------------------------------
// Kernel 1b (r6-PROVEN, 4 K-slices): reduce + bias, log-sigmoid, cumsum, pmax.
// ---------------------------------------------------------------------------
__global__ __launch_bounds__(256) void k_gates_final(
    const float* __restrict__ part, const float* __restrict__ igb, const float* __restrict__ fgb,
    float* __restrict__ ig_ws, float* __restrict__ csum_ws, float* __restrict__ pmax_ws)
{
    const int b = blockIdx.x;
    const int t = threadIdx.x;
    __shared__ float red[64][18];
    {
        const int s = t >> 2, oq = t & 3;
        float4 sum = make_float4(0.f, 0.f, 0.f, 0.f);
        #pragma unroll
        for (int ksl = 0; ksl < 4; ++ksl) {
            const float4 p = *reinterpret_cast<const float4*>(
                part + (((size_t)ksl * 256 + b) * 64 + s) * 16 + oq * 4);
            sum.x += p.x; sum.y += p.y; sum.z += p.z; sum.w += p.w;
        }
        red[s][oq * 4 + 0] = sum.x; red[s][oq * 4 + 1] = sum.y;
        red[s][oq * 4 + 2] = sum.z; red[s][oq * 4 + 3] = sum.w;
    }
    __syncthreads();
    if (t < 64) {
        const int s = t;
        #pragma unroll
        for (int h = 0; h < 8; ++h) {
            float ig = red[s][h]     + igb[h];
            float fg = red[s][8 + h] + fgb[h];
            float lf = logsigf(fg);
            float cs = lf;
            #pragma unroll
            for (int d = 1; d < 64; d <<= 1) {
                float o = __shfl_up(cs, (unsigned)d, 64);
                if (s >= d) cs += o;
            }
            float pm = ig - cs;
            #pragma unroll
            for (int d = 1; d < 64; d <<= 1) {
                float o = __shfl_up(pm, (unsigned)d, 64);
                if (s >= d) pm = fmaxf(pm, o);
            }
            const int base = b * NHH + h;
            ig_ws[base * SS + s] = ig;
            csum_ws[base * 65 + s + 1] = cs;
            if (s == 0) csum_ws[base * 65] = 0.0f;
            pmax_ws[base * SS + s] = pm;
        }
    }
}

// ---------------------------------------------------------------------------
// Kernel 2 (r13-PROVEN): khop via split-precision MFMA.
// ---------------------------------------------------------------------------
__global__ __launch_bounds__(256) void k_khop(
    const float* __restrict__ q, const float* __restrict__ rpe, const int* __restrict__ hops,
    float* __restrict__ khop_ws)
{
    __shared__ unsigned short Phi[64 * 136];
    __shared__ unsigned short Plo[64 * 136];
    const int v = blockIdx.x;
    const int h = blockIdx.y;
    const int t = threadIdx.x;
    const int w = t >> 6, l = t & 63, c = l & 15, g = l >> 4;

    // ---- gather PE rows 0..v, split hi/lo (2 cols per iteration) ----
    const int npair = (v + 1) * 64;
    unsigned* PhiU = reinterpret_cast<unsigned*>(Phi);
    unsigned* PloU = reinterpret_cast<unsigned*>(Plo);
    for (int idx = t; idx < npair; idx += 256) {
        const int m = idx >> 6, cp = idx & 63;
        const float2 x = *reinterpret_cast<const float2*>(
            rpe + (size_t)hops[v * SS + m] * DIMM + h * DHH + 2 * cp);
        unsigned hi, lo;
        split2(x.x, x.y, hi, lo);
        PhiU[m * 68 + cp] = hi;
        PloU[m * 68 + cp] = lo;
    }
    __syncthreads();

    const int ntiles = (v >> 4) + 1;
    union bfu { unsigned u[4]; bf16x8 vv; };
    #pragma unroll
    for (int ms = 0; ms < 4; ++ms) {
        const int brow = 64 * w + 16 * ms + c;
        const float* qbase = q + ((size_t)brow * SS + v) * DIMM + h * DHH + 8 * g;
        bfu qhi[4], qlo[4];
        #pragma unroll
        for (int kk = 0; kk < 4; ++kk) {
            const float4 f0 = *reinterpret_cast<const float4*>(qbase + 32 * kk);
            const float4 f1 = *reinterpret_cast<const float4*>(qbase + 32 * kk + 4);
            split2(f0.x, f0.y, qhi[kk].u[0], qlo[kk].u[0]);
            split2(f0.z, f0.w, qhi[kk].u[1], qlo[kk].u[1]);
            split2(f1.x, f1.y, qhi[kk].u[2], qlo[kk].u[2]);
            split2(f1.z, f1.w, qhi[kk].u[3], qlo[kk].u[3]);
        }
        for (int n = 0; n < ntiles; ++n) {       // wave-uniform bound
            f32x4 acc;
            acc[0] = 0.f; acc[1] = 0.f; acc[2] = 0.f; acc[3] = 0.f;
            #pragma unroll
            for (int kk = 0; kk < 4; ++kk) {
                const int off = (16 * n + c) * 136 + 32 * kk + 8 * g;
                bf16x8 bhi = *reinterpret_cast<const bf16x8*>(&Phi[off]);
                bf16x8 blo = *reinterpret_cast<const bf16x8*>(&Plo[off]);
                acc = __builtin_amdgcn_mfma_f32_16x16x32_bf16(qhi[kk].vv, bhi, acc, 0, 0, 0);
                acc = __builtin_amdgcn_mfma_f32_16x16x32_bf16(qlo[kk].vv, bhi, acc, 0, 0, 0);
                acc = __builtin_amdgcn_mfma_f32_16x16x32_bf16(qhi[kk].vv, blo, acc, 0, 0, 0);
            }
            #pragma unroll
            for (int reg = 0; reg < 4; ++reg) {
                const int bo = 64 * w + 16 * ms + 4 * g + reg;   // D row -> batch
                khop_ws[(((size_t)bo * NHH + h) * SS + v) * SS + 16 * n + c] = acc[reg];
            }
        }
    }
}

// ---------------------------------------------------------------------------
// Kernel 3 (r13-PROVEN): split-QK^T w/ causal tile-skip, khop lane-exact regs,
// in-register D-weight/normalizer, bf16 Cn, VT-swizzled MFMA PV, in-register LN.
// ---------------------------------------------------------------------------
__global__ __launch_bounds__(256) void k_attn(
    const float* __restrict__ q, const float* __restrict__ k, const float* __restrict__ v,
    const float* __restrict__ lnw, const float* __restrict__ lnb,
    const float* __restrict__ ig_ws, const float* __restrict__ csum_ws,
    const float* __restrict__ pmax_ws, const float* __restrict__ khop_ws,
    float* __restrict__ out)
{
    __shared__ __attribute__((aligned(16))) unsigned short Kspl[2 * 64 * 136]; // Khi|Klo -> VT+Cn
    __shared__ float csum_s[65];
    __shared__ float ig_s[64];
    __shared__ float pmax_s[64];
    __shared__ float lnw_s[128];
    __shared__ float lnb_s[128];

    const int bid = blockIdx.x;
    const int b = bid >> 3, h = bid & 7;
    const int t = threadIdx.x;
    const int w = t >> 6, l = t & 63, c = l & 15, g = l >> 4;
    const float rs_dh = 0.08838834764831845f;  // 1/sqrt(128)

    unsigned short* Khi = Kspl;               // [64][136]
    unsigned short* Klo = Kspl + 64 * 136;    // [64][136]

    // ---- issue V loads into registers early (written to VT after QK^T) ----
    float4 vreg[2][4];
    #pragma unroll
    for (int it = 0; it < 2; ++it) {
        const int u = t + 256 * it;
        const int jp = u >> 4, seg8 = u & 15;
        const float* r0 = v + ((size_t)(b * 64 + 2 * jp)) * 1024 + h * 128 + seg8 * 8;
        vreg[it][0] = *reinterpret_cast<const float4*>(r0);
        vreg[it][1] = *reinterpret_cast<const float4*>(r0 + 4);
        vreg[it][2] = *reinterpret_cast<const float4*>(r0 + 1024);
        vreg[it][3] = *reinterpret_cast<const float4*>(r0 + 1028);
    }

    // ---- khop lane-exact into registers (causal tiles n<=w only) ----
    float kh[4][4];
    {
        const float* khb = khop_ws + ((size_t)(b * NHH + h) * SS) * SS;
        #pragma unroll
        for (int n = 0; n < 4; ++n) {
            if (n > w) continue;               // wave-uniform
            #pragma unroll
            for (int reg = 0; reg < 4; ++reg) {
                const int i = 16 * w + 4 * g + reg;
                kh[n][reg] = khb[(size_t)i * SS + 16 * n + c];
            }
        }
    }

    // ---- stage K as hi/lo split bf16 (scaled by 1/sqrt(DH) BEFORE split) ----
    #pragma unroll
    for (int it = 0; it < 2; ++it) {
        const int u = t + 256 * it;
        const int row = u >> 3, seg = u & 7;
        const float* kp = k + ((size_t)(b * 64 + row)) * 1024 + h * 128;
        #pragma unroll
        for (int e = 0; e < 2; ++e) {
            const int col = e * 64 + seg * 8;
            const float4 ya = *reinterpret_cast<const float4*>(kp + col);
            const float4 yb = *reinterpret_cast<const float4*>(kp + col + 4);
            unsigned* dh = reinterpret_cast<unsigned*>(&Khi[row * 136 + col]);
            unsigned* dl = reinterpret_cast<unsigned*>(&Klo[row * 136 + col]);
            split2(ya.x * rs_dh, ya.y * rs_dh, dh[0], dl[0]);
            split2(ya.z * rs_dh, ya.w * rs_dh, dh[1], dl[1]);
            split2(yb.x * rs_dh, yb.y * rs_dh, dh[2], dl[2]);
            split2(yb.z * rs_dh, yb.w * rs_dh, dh[3], dl[3]);
        }
    }
    const int cb = b * NHH + h;
    if (t < 65) csum_s[t] = csum_ws[cb * 65 + t];
    if (t >= 128 && t < 192) ig_s[t - 128] = ig_ws[cb * SS + (t - 128)];
    if (t >= 192) pmax_s[t - 192] = pmax_ws[cb * SS + (t - 192)];
    if (t < 128) lnw_s[t] = lnw[h * 128 + t];
    else if (t < 256) lnb_s[t - 128] = lnb[h * 128 + (t - 128)];

    // ---- Q A-frags from global, split hi/lo in registers (lane-exact reads) ----
    union bfu { unsigned u[4]; bf16x8 v; };
    bfu qhi[4], qlo[4];
    {
        const int qrow = 16 * w + c;
        const float* qbase = q + ((size_t)(b * 64 + qrow)) * 1024 + h * 128 + 8 * g;
        #pragma unroll
        for (int kk = 0; kk < 4; ++kk) {
            const float4 f0 = *reinterpret_cast<const float4*>(qbase + 32 * kk);
            const float4 f1 = *reinterpret_cast<const float4*>(qbase + 32 * kk + 4);
            split2(f0.x, f0.y, qhi[kk].u[0], qlo[kk].u[0]);
            split2(f0.z, f0.w, qhi[kk].u[1], qlo[kk].u[1]);
            split2(f1.x, f1.y, qhi[kk].u[2], qlo[kk].u[2]);
            split2(f1.z, f1.w, qhi[kk].u[3], qlo[kk].u[3]);
        }
    }
    __syncthreads();

    // ---- QK^T via 3-pass split MFMA on causal tiles (n<=w) ----
    f32x4 acc[4];
    #pragma unroll
    for (int n = 0; n < 4; ++n) { acc[n][0]=0.f; acc[n][1]=0.f; acc[n][2]=0.f; acc[n][3]=0.f; }
    #pragma unroll
    for (int kk = 0; kk < 4; ++kk) {
        #pragma unroll
        for (int n = 0; n < 4; ++n) {
            if (n > w) continue;               // wave-uniform causal skip
            const int off = (16 * n + c) * 136 + 32 * kk + 8 * g;
            bf16x8 bhi = *reinterpret_cast<const bf16x8*>(&Khi[off]);
            bf16x8 blo = *reinterpret_cast<const bf16x8*>(&Klo[off]);
            acc[n] = __builtin_amdgcn_mfma_f32_16x16x32_bf16(qhi[kk].v, bhi, acc[n], 0, 0, 0);
            acc[n] = __builtin_amdgcn_mfma_f32_16x16x32_bf16(qlo[kk].v, bhi, acc[n], 0, 0, 0);
            acc[n] = __builtin_amdgcn_mfma_f32_16x16x32_bf16(qhi[kk].v, blo, acc[n], 0, 0, 0);
        }
    }
    __syncthreads();   // Khi/Klo now dead

    // ---- write V^T (bf16, XOR-swizzled) into dead K region ----
    unsigned short* VT = Kspl;                 // swizzled-byte region
    unsigned short* Cn = Kspl + 128 * 72;      // [64][72] bf16
    #pragma unroll
    for (int it = 0; it < 2; ++it) {
        const int u = t + 256 * it;
        const int jp = u >> 4, seg8 = u & 15;
        float v0[8], v1[8];
        v0[0]=vreg[it][0].x; v0[1]=vreg[it][0].y; v0[2]=vreg[it][0].z; v0[3]=vreg[it][0].w;
        v0[4]=vreg[it][1].x; v0[5]=vreg[it][1].y; v0[6]=vreg[it][1].z; v0[7]=vreg[it][1].w;
        v1[0]=vreg[it][2].x; v1[1]=vreg[it][2].y; v1[2]=vreg[it][2].z; v1[3]=vreg[it][2].w;
        v1[4]=vreg[it][3].x; v1[5]=vreg[it][3].y; v1[6]=vreg[it][3].z; v1[7]=vreg[it][3].w;
        #pragma unroll
        for (int m = 0; m < 8; ++m) {
            const int cc = seg8 * 8 + m;
            unsigned byte = (unsigned)(cc * 144 + 4 * jp);
            byte ^= ((cc >> 3) & 7) << 4;
            *reinterpret_cast<unsigned*>(reinterpret_cast<char*>(VT) + byte) = pk2(v0[m], v1[m]);
        }
    }

    // ---- D-weight + rowsum + normalizer in fragment registers ----
    {
        float mi[4], rs[4];
        #pragma unroll
        for (int reg = 0; reg < 4; ++reg) {
            const int i = 16 * w + 4 * g + reg;
            mi[reg] = csum_s[i + 1] + pmax_s[i];
            rs[reg] = 0.0f;
        }
        #pragma unroll
        for (int n = 0; n < 4; ++n) {
            if (n > w) continue;               // acc/kh zero/unused beyond causal edge
            const int j = 16 * n + c;
            const float cj = csum_s[j + 1], igj = ig_s[j];
            #pragma unroll
            for (int reg = 0; reg < 4; ++reg) {
                const int i = 16 * w + 4 * g + reg;
                float val = 0.0f;
                if (j <= i) {
                    const float sc = acc[n][reg] + kh[n][reg];
                    val = sc * __expf(csum_s[i + 1] - cj + igj - mi[reg]);
                }
                acc[n][reg] = val;
                rs[reg] += val;
            }
        }
        #pragma unroll
        for (int reg = 0; reg < 4; ++reg) {
            float r = rs[reg];
            r += __shfl_xor(r, 1); r += __shfl_xor(r, 2);
            r += __shfl_xor(r, 4); r += __shfl_xor(r, 8);
            const float nrm = fmaxf(fabsf(r), __expf(-mi[reg]));
            const float inv = 1.0f / (nrm + 1e-6f);
            const int i = 16 * w + 4 * g + reg;
            #pragma unroll
            for (int n = 0; n < 4; ++n) {        // full range: acc[n>w]=0 -> Cn=0
                const int j = 16 * n + c;
                Cn[i * 72 + j] = f2bh(acc[n][reg] * inv);
            }
        }
    }
    __syncthreads();

    // ---- PV via MFMA: H[16-row strip][128] per wave ----
    f32x4 hacc[8];
    #pragma unroll
    for (int n = 0; n < 8; ++n) { hacc[n][0]=0.f; hacc[n][1]=0.f; hacc[n][2]=0.f; hacc[n][3]=0.f; }
    #pragma unroll
    for (int ks = 0; ks < 2; ++ks) {
        bf16x8 a = *reinterpret_cast<const bf16x8*>(&Cn[(16 * w + c) * 72 + 32 * ks + 8 * g]);
        #pragma unroll
        for (int n = 0; n < 8; ++n) {
            const int cc = 16 * n + c;
            unsigned byte = (unsigned)(cc * 144 + 64 * ks + 16 * g);
            byte ^= ((cc >> 3) & 7) << 4;
            bf16x8 bv = *reinterpret_cast<const bf16x8*>(reinterpret_cast<const char*>(VT) + byte);
            hacc[n] = __builtin_amdgcn_mfma_f32_16x16x32_bf16(a, bv, hacc[n], 0, 0, 0);
        }
    }

    // ---- fused per-head LayerNorm + output (in fragment registers) ----
    #pragma unroll
    for (int reg = 0; reg < 4; ++reg) {
        float s1 = 0.f, s2 = 0.f;
        #pragma unroll
        for (int n = 0; n < 8; ++n) { const float x = hacc[n][reg]; s1 += x; s2 = fmaf(x, x, s2); }
        s1 += __shfl_xor(s1, 1); s1 += __shfl_xor(s1, 2);
        s1 += __shfl_xor(s1, 4); s1 += __shfl_xor(s1, 8);
        s2 += __shfl_xor(s2, 1); s2 += __shfl_xor(s2, 2);
        s2 += __shfl_xor(s2, 4); s2 += __shfl_xor(s2, 8);
        const float mu = s1 * (1.0f / 128.0f);
        const float var = s2 * (1.0f / 128.0f) - mu * mu;
        const float rstd = rsqrtf(var + 1e-5f);
        const int io = 16 * w + 4 * g + reg;
        float* op = out + (((size_t)(b * 64 + io)) * 8 + h) * 128;
        #pragma unroll
        for (int n = 0; n < 8; ++n) {
            const int cc = 16 * n + c;
            op[cc] = (hacc[n][reg] - mu) * rstd * (1.0f + lnw_s[cc]) + lnb_s[cc];
        }
    }
}

extern "C" void kernel_launch(void* const* d_in, const int* in_sizes, int n_in,
                              void* d_out, int out_size, void* d_ws, size_t ws_size,
                              hipStream_t stream) {
    const float* q   = (const float*)d_in[0];
    const float* k   = (const float*)d_in[1];
    const float* v   = (const float*)d_in[2];
    const float* igw = (const float*)d_in[3];
    const float* igb = (const float*)d_in[4];
    const float* fgw = (const float*)d_in[5];
    const float* fgb = (const float*)d_in[6];
    const float* rpe = (const float*)d_in[7];
    const float* lnw = (const float*)d_in[8];
    const float* lnb = (const float*)d_in[9];
    const int*  hops = (const int*)d_in[10];
    float* out = (float*)d_out;

    // ws (floats): ig[131072] | pmax[131072] | csum[133120] | REGION (aliased):
    //   gate partials ([4][256][64][16] = 1.05M f32) consumed by k_gates_final
    //   BEFORE k_khop overwrites the region as khop_ws (8.39M f32).
    float* ig_ws   = (float*)d_ws;
    float* pmax_ws = ig_ws + 131072;
    float* csum_ws = pmax_ws + 131072;
    float* part    = csum_ws + 133120;
    float* khop_ws = part;

    hipLaunchKernelGGL(k_gate_mfma, dim3(1024), dim3(256), 0, stream,
                       q, k, v, igw, fgw, part);
    hipLaunchKernelGGL(k_gates_final, dim3(BB), dim3(256), 0, stream,
                       part, igb, fgb, ig_ws, csum_ws, pmax_ws);
    hipLaunchKernelGGL(k_khop, dim3(SS, NHH), dim3(256), 0, stream,
                       q, rpe, hops, khop_ws);
    hipLaunchKernelGGL(k_attn, dim3(BB * NHH), dim3(256), 0, stream,
                       q, k, v, lnw, lnb, ig_ws, csum_ws, pmax_ws, khop_ws, out);
}

// Round 20
// 118.688 us; speedup vs baseline: 1.1017x; 1.1017x over previous
//
#include <hip/hip_runtime.h>
#include <math.h>

#define BB 256
#define SS 64
#define DIMM 1024
#define NHH 8
#define DHH 128

typedef short bf16x8 __attribute__((ext_vector_type(8)));
typedef float f32x4 __attribute__((ext_vector_type(4)));

__device__ __forceinline__ unsigned cvtpk(float lo, float hi) {
    unsigned r;
    asm("v_cvt_pk_bf16_f32 %0, %1, %2" : "=v"(r) : "v"(lo), "v"(hi));
    return r;
}
__device__ __forceinline__ unsigned pk2(float lo, float hi) { return cvtpk(lo, hi); }
__device__ __forceinline__ unsigned short f2bh(float x) {
    return (unsigned short)(cvtpk(x, 0.0f) & 0xFFFFu);
}
__device__ __forceinline__ float bf2f(unsigned short b) {
    union { unsigned u; float f; } x{((unsigned)b) << 16};
    return x.f;
}
__device__ __forceinline__ void split2(float a, float b, unsigned& hi, unsigned& lo) {
    hi = cvtpk(a, b);
    const float ha = __uint_as_float(hi << 16);
    const float hb = __uint_as_float(hi & 0xFFFF0000u);
    lo = cvtpk(a - ha, b - hb);
}
__device__ __forceinline__ float logsigf(float x) {
    return fminf(x, 0.0f) - log1pf(__expf(-fabsf(x)));
}

// ---------------------------------------------------------------------------
// Gate body (r17-PROVEN) as device function. Xs[64*264], Ws[16*264] shorts.
// ---------------------------------------------------------------------------
__device__ __forceinline__ void gate_body(
    int b, int ksl, int t,
    const float* __restrict__ q, const float* __restrict__ k, const float* __restrict__ v,
    const float* __restrict__ igw, const float* __restrict__ fgw,
    float* __restrict__ part, unsigned short* Xs, unsigned short* Ws)
{
    const int w = t >> 6, l = t & 63, c = l & 15, g = l >> 4;
    f32x4 acc;
    acc[0] = 0.f; acc[1] = 0.f; acc[2] = 0.f; acc[3] = 0.f;

    for (int step = 0; step < 3; ++step) {
        const int kc = ksl * 3 + step;
        const int tensor = kc >> 2;
        const float* src = (tensor == 0) ? q : (tensor == 1) ? k : v;
        src += (size_t)b * 65536 + (kc & 3) * 256;

        float4 xb[16];
        #pragma unroll
        for (int i = 0; i < 16; ++i)
            xb[i] = *reinterpret_cast<const float4*>(src + (size_t)(4 * i + w) * 1024 + 4 * l);
        const int o = t >> 4, wseg = t & 15;
        const float* wp = (o < 8 ? igw + o * 3072 : fgw + (o - 8) * 3072)
                          + ksl * 768 + step * 256;
        float4 wb4[4];
        #pragma unroll
        for (int e = 0; e < 4; ++e)
            wb4[e] = *reinterpret_cast<const float4*>(wp + e * 64 + wseg * 4);

        #pragma unroll
        for (int i = 0; i < 16; ++i) {
            unsigned* dp = reinterpret_cast<unsigned*>(&Xs[(4 * i + w) * 264 + 4 * l]);
            dp[0] = pk2(xb[i].x, xb[i].y); dp[1] = pk2(xb[i].z, xb[i].w);
        }
        #pragma unroll
        for (int e = 0; e < 4; ++e) {
            unsigned* dp = reinterpret_cast<unsigned*>(&Ws[o * 264 + e * 64 + wseg * 4]);
            dp[0] = pk2(wb4[e].x, wb4[e].y); dp[1] = pk2(wb4[e].z, wb4[e].w);
        }
        __syncthreads();
        #pragma unroll
        for (int kk = 0; kk < 8; ++kk) {
            bf16x8 a  = *reinterpret_cast<const bf16x8*>(&Xs[(16 * w + c) * 264 + 32 * kk + 8 * g]);
            bf16x8 bw = *reinterpret_cast<const bf16x8*>(&Ws[c * 264 + 32 * kk + 8 * g]);
            acc = __builtin_amdgcn_mfma_f32_16x16x32_bf16(a, bw, acc, 0, 0, 0);
        }
        __syncthreads();
    }
    float* pb = part + (((size_t)ksl * 256 + b) * 64) * 16;
    #pragma unroll
    for (int reg = 0; reg < 4; ++reg) {
        const int s = 16 * w + 4 * g + reg;
        pb[s * 16 + c] = acc[reg];
    }
}

// ---------------------------------------------------------------------------
// khop body (r13-PROVEN) as device function. Phi/Plo[64*136] shorts.
// ---------------------------------------------------------------------------
__device__ __forceinline__ void khop_body(
    int vb, int h, int t,
    const float* __restrict__ q, const float* __restrict__ rpe, const int* __restrict__ hops,
    float* __restrict__ khop_ws, unsigned short* Phi, unsigned short* Plo)
{
    const int w = t >> 6, l = t & 63, c = l & 15, g = l >> 4;
    const int npair = (vb + 1) * 64;
    unsigned* PhiU = reinterpret_cast<unsigned*>(Phi);
    unsigned* PloU = reinterpret_cast<unsigned*>(Plo);
    for (int idx = t; idx < npair; idx += 256) {
        const int m = idx >> 6, cp = idx & 63;
        const float2 x = *reinterpret_cast<const float2*>(
            rpe + (size_t)hops[vb * SS + m] * DIMM + h * DHH + 2 * cp);
        unsigned hi, lo;
        split2(x.x, x.y, hi, lo);
        PhiU[m * 68 + cp] = hi;
        PloU[m * 68 + cp] = lo;
    }
    __syncthreads();

    const int ntiles = (vb >> 4) + 1;
    union bfu { unsigned u[4]; bf16x8 vv; };
    #pragma unroll
    for (int ms = 0; ms < 4; ++ms) {
        const int brow = 64 * w + 16 * ms + c;
        const float* qbase = q + ((size_t)brow * SS + vb) * DIMM + h * DHH + 8 * g;
        bfu qhi[4], qlo[4];
        #pragma unroll
        for (int kk = 0; kk < 4; ++kk) {
            const float4 f0 = *reinterpret_cast<const float4*>(qbase + 32 * kk);
            const float4 f1 = *reinterpret_cast<const float4*>(qbase + 32 * kk + 4);
            split2(f0.x, f0.y, qhi[kk].u[0], qlo[kk].u[0]);
            split2(f0.z, f0.w, qhi[kk].u[1], qlo[kk].u[1]);
            split2(f1.x, f1.y, qhi[kk].u[2], qlo[kk].u[2]);
            split2(f1.z, f1.w, qhi[kk].u[3], qlo[kk].u[3]);
        }
        for (int n = 0; n < ntiles; ++n) {
            f32x4 acc;
            acc[0] = 0.f; acc[1] = 0.f; acc[2] = 0.f; acc[3] = 0.f;
            #pragma unroll
            for (int kk = 0; kk < 4; ++kk) {
                const int off = (16 * n + c) * 136 + 32 * kk + 8 * g;
                bf16x8 bhi = *reinterpret_cast<const bf16x8*>(&Phi[off]);
                bf16x8 blo = *reinterpret_cast<const bf16x8*>(&Plo[off]);
                acc = __builtin_amdgcn_mfma_f32_16x16x32_bf16(qhi[kk].vv, bhi, acc, 0, 0, 0);
                acc = __builtin_amdgcn_mfma_f32_16x16x32_bf16(qlo[kk].vv, bhi, acc, 0, 0, 0);
                acc = __builtin_amdgcn_mfma_f32_16x16x32_bf16(qhi[kk].vv, blo, acc, 0, 0, 0);
            }
            #pragma unroll
            for (int reg = 0; reg < 4; ++reg) {
                const int bo = 64 * w + 16 * ms + 4 * g + reg;
                khop_ws[(((size_t)bo * NHH + h) * SS + vb) * SS + 16 * n + c] = acc[reg];
            }
        }
    }
}

// ---------------------------------------------------------------------------
// FUSED: khop blocks (0..511) + gate blocks (512..1535). No data dependency;
// khop's MFMA-dense waves fill the machine during gate's latency stalls.
// ---------------------------------------------------------------------------
__global__ __launch_bounds__(256) void k_gate_khop(
    const float* __restrict__ q, const float* __restrict__ k, const float* __restrict__ v,
    const float* __restrict__ igw, const float* __restrict__ fgw,
    const float* __restrict__ rpe, const int* __restrict__ hops,
    float* __restrict__ part, float* __restrict__ khop_ws)
{
    __shared__ __attribute__((aligned(16))) char smem[80 * 264 * 2];  // 42240 B
    const int bid = blockIdx.x;
    const int t = threadIdx.x;
    if (bid < 512) {
        unsigned short* Phi = reinterpret_cast<unsigned short*>(smem);
        khop_body(bid & 63, bid >> 6, t, q, rpe, hops, khop_ws, Phi, Phi + 64 * 136);
    } else {
        const int gb = bid - 512;
        unsigned short* Xs = reinterpret_cast<unsigned short*>(smem);
        gate_body(gb & 255, gb >> 8, t, q, k, v, igw, fgw, part, Xs, Xs + 64 * 264);
    }
}

// ---------------------------------------------------------------------------
// Standalone fallbacks (r17-PROVEN, aliased-workspace serial path).
// ---------------------------------------------------------------------------
__global__ __launch_bounds__(256) void k_gate_mfma(
    const float* __restrict__ q, const float* __restrict__ k, const float* __restrict__ v,
    const float* __restrict__ igw, const float* __restrict__ fgw,
    float* __restrict__ part)
{
    __shared__ unsigned short Xs[64 * 264];
    __shared__ unsigned short Ws[16 * 264];
    gate_body(blockIdx.x & 255, blockIdx.x >> 8, threadIdx.x, q, k, v, igw, fgw, part, Xs, Ws);
}

__global__ __launch_bounds__(256) void k_khop(
    const float* __restrict__ q, const float* __restrict__ rpe, const int* __restrict__ hops,
    float* __restrict__ khop_ws)
{
    __shared__ unsigned short Phi[64 * 136];
    __shared__ unsigned short Plo[64 * 136];
    khop_body(blockIdx.x, blockIdx.y, threadIdx.x, q, rpe, hops, khop_ws, Phi, Plo);
}

// ---------------------------------------------------------------------------
// Kernel 1b (r6-PROVEN, 4 K-slices): reduce + bias, log-sigmoid, cumsum, pmax.
// ---------------------------------------------------------------------------
__global__ __launch_bounds__(256) void k_gates_final(
    const float* __restrict__ part, const float* __restrict__ igb, const float* __restrict__ fgb,
    float* __restrict__ ig_ws, float* __restrict__ csum_ws, float* __restrict__ pmax_ws)
{
    const int b = blockIdx.x;
    const int t = threadIdx.x;
    __shared__ float red[64][18];
    {
        const int s = t >> 2, oq = t & 3;
        float4 sum = make_float4(0.f, 0.f, 0.f, 0.f);
        #pragma unroll
        for (int ksl = 0; ksl < 4; ++ksl) {
            const float4 p = *reinterpret_cast<const float4*>(
                part + (((size_t)ksl * 256 + b) * 64 + s) * 16 + oq * 4);
            sum.x += p.x; sum.y += p.y; sum.z += p.z; sum.w += p.w;
        }
        red[s][oq * 4 + 0] = sum.x; red[s][oq * 4 + 1] = sum.y;
        red[s][oq * 4 + 2] = sum.z; red[s][oq * 4 + 3] = sum.w;
    }
    __syncthreads();
    if (t < 64) {
        const int s = t;
        #pragma unroll
        for (int h = 0; h < 8; ++h) {
            float ig = red[s][h]     + igb[h];
            float fg = red[s][8 + h] + fgb[h];
            float lf = logsigf(fg);
            float cs = lf;
            #pragma unroll
            for (int d = 1; d < 64; d <<= 1) {
                float o = __shfl_up(cs, (unsigned)d, 64);
                if (s >= d) cs += o;
            }
            float pm = ig - cs;
            #pragma unroll
            for (int d = 1; d < 64; d <<= 1) {
                float o = __shfl_up(pm, (unsigned)d, 64);
                if (s >= d) pm = fmaxf(pm, o);
            }
            const int base = b * NHH + h;
            ig_ws[base * SS + s] = ig;
            csum_ws[base * 65 + s + 1] = cs;
            if (s == 0) csum_ws[base * 65] = 0.0f;
            pmax_ws[base * SS + s] = pm;
        }
    }
}

// ---------------------------------------------------------------------------
// Kernel 3 (r13-PROVEN): split-QK^T w/ causal tile-skip, khop lane-exact regs,
// in-register D-weight/normalizer, bf16 Cn, VT-swizzled MFMA PV, in-register LN.
// ---------------------------------------------------------------------------
__global__ __launch_bounds__(256) void k_attn(
    const float* __restrict__ q, const float* __restrict__ k, const float* __restrict__ v,
    const float* __restrict__ lnw, const float* __restrict__ lnb,
    const float* __restrict__ ig_ws, const float* __restrict__ csum_ws,
    const float* __restrict__ pmax_ws, const float* __restrict__ khop_ws,
    float* __restrict__ out)
{
    __shared__ __attribute__((aligned(16))) unsigned short Kspl[2 * 64 * 136];
    __shared__ float csum_s[65];
    __shared__ float ig_s[64];
    __shared__ float pmax_s[64];
    __shared__ float lnw_s[128];
    __shared__ float lnb_s[128];

    const int bid = blockIdx.x;
    const int b = bid >> 3, h = bid & 7;
    const int t = threadIdx.x;
    const int w = t >> 6, l = t & 63, c = l & 15, g = l >> 4;
    const float rs_dh = 0.08838834764831845f;

    unsigned short* Khi = Kspl;
    unsigned short* Klo = Kspl + 64 * 136;

    float4 vreg[2][4];
    #pragma unroll
    for (int it = 0; it < 2; ++it) {
        const int u = t + 256 * it;
        const int jp = u >> 4, seg8 = u & 15;
        const float* r0 = v + ((size_t)(b * 64 + 2 * jp)) * 1024 + h * 128 + seg8 * 8;
        vreg[it][0] = *reinterpret_cast<const float4*>(r0);
        vreg[it][1] = *reinterpret_cast<const float4*>(r0 + 4);
        vreg[it][2] = *reinterpret_cast<const float4*>(r0 + 1024);
        vreg[it][3] = *reinterpret_cast<const float4*>(r0 + 1028);
    }

    float kh[4][4];
    {
        const float* khb = khop_ws + ((size_t)(b * NHH + h) * SS) * SS;
        #pragma unroll
        for (int n = 0; n < 4; ++n) {
            if (n > w) continue;
            #pragma unroll
            for (int reg = 0; reg < 4; ++reg) {
                const int i = 16 * w + 4 * g + reg;
                kh[n][reg] = khb[(size_t)i * SS + 16 * n + c];
            }
        }
    }

    #pragma unroll
    for (int it = 0; it < 2; ++it) {
        const int u = t + 256 * it;
        const int row = u >> 3, seg = u & 7;
        const float* kp = k + ((size_t)(b * 64 + row)) * 1024 + h * 128;
        #pragma unroll
        for (int e = 0; e < 2; ++e) {
            const int col = e * 64 + seg * 8;
            const float4 ya = *reinterpret_cast<const float4*>(kp + col);
            const float4 yb = *reinterpret_cast<const float4*>(kp + col + 4);
            unsigned* dh = reinterpret_cast<unsigned*>(&Khi[row * 136 + col]);
            unsigned* dl = reinterpret_cast<unsigned*>(&Klo[row * 136 + col]);
            split2(ya.x * rs_dh, ya.y * rs_dh, dh[0], dl[0]);
            split2(ya.z * rs_dh, ya.w * rs_dh, dh[1], dl[1]);
            split2(yb.x * rs_dh, yb.y * rs_dh, dh[2], dl[2]);
            split2(yb.z * rs_dh, yb.w * rs_dh, dh[3], dl[3]);
        }
    }
    const int cb = b * NHH + h;
    if (t < 65) csum_s[t] = csum_ws[cb * 65 + t];
    if (t >= 128 && t < 192) ig_s[t - 128] = ig_ws[cb * SS + (t - 128)];
    if (t >= 192) pmax_s[t - 192] = pmax_ws[cb * SS + (t - 192)];
    if (t < 128) lnw_s[t] = lnw[h * 128 + t];
    else if (t < 256) lnb_s[t - 128] = lnb[h * 128 + (t - 128)];

    union bfu { unsigned u[4]; bf16x8 v; };
    bfu qhi[4], qlo[4];
    {
        const int qrow = 16 * w + c;
        const float* qbase = q + ((size_t)(b * 64 + qrow)) * 1024 + h * 128 + 8 * g;
        #pragma unroll
        for (int kk = 0; kk < 4; ++kk) {
            const float4 f0 = *reinterpret_cast<const float4*>(qbase + 32 * kk);
            const float4 f1 = *reinterpret_cast<const float4*>(qbase + 32 * kk + 4);
            split2(f0.x, f0.y, qhi[kk].u[0], qlo[kk].u[0]);
            split2(f0.z, f0.w, qhi[kk].u[1], qlo[kk].u[1]);
            split2(f1.x, f1.y, qhi[kk].u[2], qlo[kk].u[2]);
            split2(f1.z, f1.w, qhi[kk].u[3], qlo[kk].u[3]);
        }
    }
    __syncthreads();

    f32x4 acc[4];
    #pragma unroll
    for (int n = 0; n < 4; ++n) { acc[n][0]=0.f; acc[n][1]=0.f; acc[n][2]=0.f; acc[n][3]=0.f; }
    #pragma unroll
    for (int kk = 0; kk < 4; ++kk) {
        #pragma unroll
        for (int n = 0; n < 4; ++n) {
            if (n > w) continue;
            const int off = (16 * n + c) * 136 + 32 * kk + 8 * g;
            bf16x8 bhi = *reinterpret_cast<const bf16x8*>(&Khi[off]);
            bf16x8 blo = *reinterpret_cast<const bf16x8*>(&Klo[off]);
            acc[n] = __builtin_amdgcn_mfma_f32_16x16x32_bf16(qhi[kk].v, bhi, acc[n], 0, 0, 0);
            acc[n] = __builtin_amdgcn_mfma_f32_16x16x32_bf16(qlo[kk].v, bhi, acc[n], 0, 0, 0);
            acc[n] = __builtin_amdgcn_mfma_f32_16x16x32_bf16(qhi[kk].v, blo, acc[n], 0, 0, 0);
        }
    }
    __syncthreads();

    unsigned short* VT = Kspl;
    unsigned short* Cn = Kspl + 128 * 72;
    #pragma unroll
    for (int it = 0; it < 2; ++it) {
        const int u = t + 256 * it;
        const int jp = u >> 4, seg8 = u & 15;
        float v0[8], v1[8];
        v0[0]=vreg[it][0].x; v0[1]=vreg[it][0].y; v0[2]=vreg[it][0].z; v0[3]=vreg[it][0].w;
        v0[4]=vreg[it][1].x; v0[5]=vreg[it][1].y; v0[6]=vreg[it][1].z; v0[7]=vreg[it][1].w;
        v1[0]=vreg[it][2].x; v1[1]=vreg[it][2].y; v1[2]=vreg[it][2].z; v1[3]=vreg[it][2].w;
        v1[4]=vreg[it][3].x; v1[5]=vreg[it][3].y; v1[6]=vreg[it][3].z; v1[7]=vreg[it][3].w;
        #pragma unroll
        for (int m = 0; m < 8; ++m) {
            const int cc = seg8 * 8 + m;
            unsigned byte = (unsigned)(cc * 144 + 4 * jp);
            byte ^= ((cc >> 3) & 7) << 4;
            *reinterpret_cast<unsigned*>(reinterpret_cast<char*>(VT) + byte) = pk2(v0[m], v1[m]);
        }
    }

    {
        float mi[4], rs[4];
        #pragma unroll
        for (int reg = 0; reg < 4; ++reg) {
            const int i = 16 * w + 4 * g + reg;
            mi[reg] = csum_s[i + 1] + pmax_s[i];
            rs[reg] = 0.0f;
        }
        #pragma unroll
        for (int n = 0; n < 4; ++n) {
            if (n > w) continue;
            const int j = 16 * n + c;
            const float cj = csum_s[j + 1], igj = ig_s[j];
            #pragma unroll
            for (int reg = 0; reg < 4; ++reg) {
                const int i = 16 * w + 4 * g + reg;
                float val = 0.0f;
                if (j <= i) {
                    const float sc = acc[n][reg] + kh[n][reg];
                    val = sc * __expf(csum_s[i + 1] - cj + igj - mi[reg]);
                }
                acc[n][reg] = val;
                rs[reg] += val;
            }
        }
        #pragma unroll
        for (int reg = 0; reg < 4; ++reg) {
            float r = rs[reg];
            r += __shfl_xor(r, 1); r += __shfl_xor(r, 2);
            r += __shfl_xor(r, 4); r += __shfl_xor(r, 8);
            const float nrm = fmaxf(fabsf(r), __expf(-mi[reg]));
            const float inv = 1.0f / (nrm + 1e-6f);
            const int i = 16 * w + 4 * g + reg;
            #pragma unroll
            for (int n = 0; n < 4; ++n) {
                const int j = 16 * n + c;
                Cn[i * 72 + j] = f2bh(acc[n][reg] * inv);
            }
        }
    }
    __syncthreads();

    f32x4 hacc[8];
    #pragma unroll
    for (int n = 0; n < 8; ++n) { hacc[n][0]=0.f; hacc[n][1]=0.f; hacc[n][2]=0.f; hacc[n][3]=0.f; }
    #pragma unroll
    for (int ks = 0; ks < 2; ++ks) {
        bf16x8 a = *reinterpret_cast<const bf16x8*>(&Cn[(16 * w + c) * 72 + 32 * ks + 8 * g]);
        #pragma unroll
        for (int n = 0; n < 8; ++n) {
            const int cc = 16 * n + c;
            unsigned byte = (unsigned)(cc * 144 + 64 * ks + 16 * g);
            byte ^= ((cc >> 3) & 7) << 4;
            bf16x8 bv = *reinterpret_cast<const bf16x8*>(reinterpret_cast<const char*>(VT) + byte);
            hacc[n] = __builtin_amdgcn_mfma_f32_16x16x32_bf16(a, bv, hacc[n], 0, 0, 0);
        }
    }

    #pragma unroll
    for (int reg = 0; reg < 4; ++reg) {
        float s1 = 0.f, s2 = 0.f;
        #pragma unroll
        for (int n = 0; n < 8; ++n) { const float x = hacc[n][reg]; s1 += x; s2 = fmaf(x, x, s2); }
        s1 += __shfl_xor(s1, 1); s1 += __shfl_xor(s1, 2);
        s1 += __shfl_xor(s1, 4); s1 += __shfl_xor(s1, 8);
        s2 += __shfl_xor(s2, 1); s2 += __shfl_xor(s2, 2);
        s2 += __shfl_xor(s2, 4); s2 += __shfl_xor(s2, 8);
        const float mu = s1 * (1.0f / 128.0f);
        const float var = s2 * (1.0f / 128.0f) - mu * mu;
        const float rstd = rsqrtf(var + 1e-5f);
        const int io = 16 * w + 4 * g + reg;
        float* op = out + (((size_t)(b * 64 + io)) * 8 + h) * 128;
        #pragma unroll
        for (int n = 0; n < 8; ++n) {
            const int cc = 16 * n + c;
            op[cc] = (hacc[n][reg] - mu) * rstd * (1.0f + lnw_s[cc]) + lnb_s[cc];
        }
    }
}

extern "C" void kernel_launch(void* const* d_in, const int* in_sizes, int n_in,
                              void* d_out, int out_size, void* d_ws, size_t ws_size,
                              hipStream_t stream) {
    const float* q   = (const float*)d_in[0];
    const float* k   = (const float*)d_in[1];
    const float* v   = (const float*)d_in[2];
    const float* igw = (const float*)d_in[3];
    const float* igb = (const float*)d_in[4];
    const float* fgw = (const float*)d_in[5];
    const float* fgb = (const float*)d_in[6];
    const float* rpe = (const float*)d_in[7];
    const float* lnw = (const float*)d_in[8];
    const float* lnb = (const float*)d_in[9];
    const int*  hops = (const int*)d_in[10];
    float* out = (float*)d_out;

    float* ig_ws   = (float*)d_ws;
    float* pmax_ws = ig_ws + 131072;
    float* csum_ws = pmax_ws + 131072;
    float* part    = csum_ws + 133120;

    // Fused path needs part (1.05M f32) and khop_ws (8.39M f32) disjoint:
    const size_t NEED = (size_t)(131072 + 131072 + 133120 + 1048576 + 8388608) * 4;
    if (ws_size >= NEED) {
        float* khop_ws = part + 1048576;
        hipLaunchKernelGGL(k_gate_khop, dim3(1536), dim3(256), 0, stream,
                           q, k, v, igw, fgw, rpe, hops, part, khop_ws);
        hipLaunchKernelGGL(k_gates_final, dim3(BB), dim3(256), 0, stream,
                           part, igb, fgb, ig_ws, csum_ws, pmax_ws);
        hipLaunchKernelGGL(k_attn, dim3(BB * NHH), dim3(256), 0, stream,
                           q, k, v, lnw, lnb, ig_ws, csum_ws, pmax_ws, khop_ws, out);
    } else {
        // r17-proven serial path with part/khop_ws aliased.
        float* khop_ws = part;
        hipLaunchKernelGGL(k_gate_mfma, dim3(1024), dim3(256), 0, stream,
                           q, k, v, igw, fgw, part);
        hipLaunchKernelGGL(k_gates_final, dim3(BB), dim3(256), 0, stream,
                           part, igb, fgb, ig_ws, csum_ws, pmax_ws);
        hipLaunchKernelGGL(k_khop, dim3(SS, NHH), dim3(256), 0, stream,
                           q, rpe, hops, khop_ws);
        hipLaunchKernelGGL(k_attn, dim3(BB * NHH), dim3(256), 0, stream,
                           q, k, v, lnw, lnb, ig_ws, csum_ws, pmax_ws, khop_ws, out);
    }
}

// Round 21
// 112.959 us; speedup vs baseline: 1.1576x; 1.0507x over previous
//
#include <hip/hip_runtime.h>
#include <math.h>

#define BB 256
#define SS 64
#define DIMM 1024
#define NHH 8
#define DHH 128

typedef short bf16x8 __attribute__((ext_vector_type(8)));
typedef float f32x4 __attribute__((ext_vector_type(4)));

__device__ __forceinline__ unsigned cvtpk(float lo, float hi) {
    unsigned r;
    asm("v_cvt_pk_bf16_f32 %0, %1, %2" : "=v"(r) : "v"(lo), "v"(hi));
    return r;
}
__device__ __forceinline__ unsigned pk2(float lo, float hi) { return cvtpk(lo, hi); }
__device__ __forceinline__ unsigned short f2bh(float x) {
    return (unsigned short)(cvtpk(x, 0.0f) & 0xFFFFu);
}
__device__ __forceinline__ float bf2f(unsigned short b) {
    union { unsigned u; float f; } x{((unsigned)b) << 16};
    return x.f;
}
__device__ __forceinline__ void split2(float a, float b, unsigned& hi, unsigned& lo) {
    hi = cvtpk(a, b);
    const float ha = __uint_as_float(hi << 16);
    const float hb = __uint_as_float(hi & 0xFFFF0000u);
    lo = cvtpk(a - ha, b - hb);
}
__device__ __forceinline__ float logsigf(float x) {
    return fminf(x, 0.0f) - log1pf(__expf(-fabsf(x)));
}

// ---------------------------------------------------------------------------
// Gate body (r17/r20-PROVEN). Xs[64*264], Ws[16*264] shorts.
// ---------------------------------------------------------------------------
__device__ __forceinline__ void gate_body(
    int b, int ksl, int t,
    const float* __restrict__ q, const float* __restrict__ k, const float* __restrict__ v,
    const float* __restrict__ igw, const float* __restrict__ fgw,
    float* __restrict__ part, unsigned short* Xs, unsigned short* Ws)
{
    const int w = t >> 6, l = t & 63, c = l & 15, g = l >> 4;
    f32x4 acc;
    acc[0] = 0.f; acc[1] = 0.f; acc[2] = 0.f; acc[3] = 0.f;

    for (int step = 0; step < 3; ++step) {
        const int kc = ksl * 3 + step;
        const int tensor = kc >> 2;
        const float* src = (tensor == 0) ? q : (tensor == 1) ? k : v;
        src += (size_t)b * 65536 + (kc & 3) * 256;

        float4 xb[16];
        #pragma unroll
        for (int i = 0; i < 16; ++i)
            xb[i] = *reinterpret_cast<const float4*>(src + (size_t)(4 * i + w) * 1024 + 4 * l);
        const int o = t >> 4, wseg = t & 15;
        const float* wp = (o < 8 ? igw + o * 3072 : fgw + (o - 8) * 3072)
                          + ksl * 768 + step * 256;
        float4 wb4[4];
        #pragma unroll
        for (int e = 0; e < 4; ++e)
            wb4[e] = *reinterpret_cast<const float4*>(wp + e * 64 + wseg * 4);

        #pragma unroll
        for (int i = 0; i < 16; ++i) {
            unsigned* dp = reinterpret_cast<unsigned*>(&Xs[(4 * i + w) * 264 + 4 * l]);
            dp[0] = pk2(xb[i].x, xb[i].y); dp[1] = pk2(xb[i].z, xb[i].w);
        }
        #pragma unroll
        for (int e = 0; e < 4; ++e) {
            unsigned* dp = reinterpret_cast<unsigned*>(&Ws[o * 264 + e * 64 + wseg * 4]);
            dp[0] = pk2(wb4[e].x, wb4[e].y); dp[1] = pk2(wb4[e].z, wb4[e].w);
        }
        __syncthreads();
        #pragma unroll
        for (int kk = 0; kk < 8; ++kk) {
            bf16x8 a  = *reinterpret_cast<const bf16x8*>(&Xs[(16 * w + c) * 264 + 32 * kk + 8 * g]);
            bf16x8 bw = *reinterpret_cast<const bf16x8*>(&Ws[c * 264 + 32 * kk + 8 * g]);
            acc = __builtin_amdgcn_mfma_f32_16x16x32_bf16(a, bw, acc, 0, 0, 0);
        }
        __syncthreads();
    }
    float* pb = part + (((size_t)ksl * 256 + b) * 64) * 16;
    #pragma unroll
    for (int reg = 0; reg < 4; ++reg) {
        const int s = 16 * w + 4 * g + reg;
        pb[s * 16 + c] = acc[reg];
    }
}

// ---------------------------------------------------------------------------
// khop body (r13/r20-PROVEN). Phi/Plo[64*136] shorts.
// ---------------------------------------------------------------------------
__device__ __forceinline__ void khop_body(
    int vb, int h, int t,
    const float* __restrict__ q, const float* __restrict__ rpe, const int* __restrict__ hops,
    float* __restrict__ khop_ws, unsigned short* Phi, unsigned short* Plo)
{
    const int w = t >> 6, l = t & 63, c = l & 15, g = l >> 4;
    const int npair = (vb + 1) * 64;
    unsigned* PhiU = reinterpret_cast<unsigned*>(Phi);
    unsigned* PloU = reinterpret_cast<unsigned*>(Plo);
    for (int idx = t; idx < npair; idx += 256) {
        const int m = idx >> 6, cp = idx & 63;
        const float2 x = *reinterpret_cast<const float2*>(
            rpe + (size_t)hops[vb * SS + m] * DIMM + h * DHH + 2 * cp);
        unsigned hi, lo;
        split2(x.x, x.y, hi, lo);
        PhiU[m * 68 + cp] = hi;
        PloU[m * 68 + cp] = lo;
    }
    __syncthreads();

    const int ntiles = (vb >> 4) + 1;
    union bfu { unsigned u[4]; bf16x8 vv; };
    #pragma unroll
    for (int ms = 0; ms < 4; ++ms) {
        const int brow = 64 * w + 16 * ms + c;
        const float* qbase = q + ((size_t)brow * SS + vb) * DIMM + h * DHH + 8 * g;
        bfu qhi[4], qlo[4];
        #pragma unroll
        for (int kk = 0; kk < 4; ++kk) {
            const float4 f0 = *reinterpret_cast<const float4*>(qbase + 32 * kk);
            const float4 f1 = *reinterpret_cast<const float4*>(qbase + 32 * kk + 4);
            split2(f0.x, f0.y, qhi[kk].u[0], qlo[kk].u[0]);
            split2(f0.z, f0.w, qhi[kk].u[1], qlo[kk].u[1]);
            split2(f1.x, f1.y, qhi[kk].u[2], qlo[kk].u[2]);
            split2(f1.z, f1.w, qhi[kk].u[3], qlo[kk].u[3]);
        }
        for (int n = 0; n < ntiles; ++n) {
            f32x4 acc;
            acc[0] = 0.f; acc[1] = 0.f; acc[2] = 0.f; acc[3] = 0.f;
            #pragma unroll
            for (int kk = 0; kk < 4; ++kk) {
                const int off = (16 * n + c) * 136 + 32 * kk + 8 * g;
                bf16x8 bhi = *reinterpret_cast<const bf16x8*>(&Phi[off]);
                bf16x8 blo = *reinterpret_cast<const bf16x8*>(&Plo[off]);
                acc = __builtin_amdgcn_mfma_f32_16x16x32_bf16(qhi[kk].vv, bhi, acc, 0, 0, 0);
                acc = __builtin_amdgcn_mfma_f32_16x16x32_bf16(qlo[kk].vv, bhi, acc, 0, 0, 0);
                acc = __builtin_amdgcn_mfma_f32_16x16x32_bf16(qhi[kk].vv, blo, acc, 0, 0, 0);
            }
            #pragma unroll
            for (int reg = 0; reg < 4; ++reg) {
                const int bo = 64 * w + 16 * ms + 4 * g + reg;
                khop_ws[(((size_t)bo * NHH + h) * SS + vb) * SS + 16 * n + c] = acc[reg];
            }
        }
    }
}

// ---------------------------------------------------------------------------
// FUSED (r20-PROVEN): khop blocks (0..511) + gate blocks (512..1535).
// ---------------------------------------------------------------------------
__global__ __launch_bounds__(256) void k_gate_khop(
    const float* __restrict__ q, const float* __restrict__ k, const float* __restrict__ v,
    const float* __restrict__ igw, const float* __restrict__ fgw,
    const float* __restrict__ rpe, const int* __restrict__ hops,
    float* __restrict__ part, float* __restrict__ khop_ws)
{
    __shared__ __attribute__((aligned(16))) char smem[80 * 264 * 2];  // 42240 B
    const int bid = blockIdx.x;
    const int t = threadIdx.x;
    if (bid < 512) {
        unsigned short* Phi = reinterpret_cast<unsigned short*>(smem);
        khop_body(bid & 63, bid >> 6, t, q, rpe, hops, khop_ws, Phi, Phi + 64 * 136);
    } else {
        const int gb = bid - 512;
        unsigned short* Xs = reinterpret_cast<unsigned short*>(smem);
        gate_body(gb & 255, gb >> 8, t, q, k, v, igw, fgw, part, Xs, Xs + 64 * 264);
    }
}

// ---------------------------------------------------------------------------
// Standalone fallbacks.
// ---------------------------------------------------------------------------
__global__ __launch_bounds__(256) void k_gate_mfma(
    const float* __restrict__ q, const float* __restrict__ k, const float* __restrict__ v,
    const float* __restrict__ igw, const float* __restrict__ fgw,
    float* __restrict__ part)
{
    __shared__ unsigned short Xs[64 * 264];
    __shared__ unsigned short Ws[16 * 264];
    gate_body(blockIdx.x & 255, blockIdx.x >> 8, threadIdx.x, q, k, v, igw, fgw, part, Xs, Ws);
}

__global__ __launch_bounds__(256) void k_khop(
    const float* __restrict__ q, const float* __restrict__ rpe, const int* __restrict__ hops,
    float* __restrict__ khop_ws)
{
    __shared__ unsigned short Phi[64 * 136];
    __shared__ unsigned short Plo[64 * 136];
    khop_body(blockIdx.x, blockIdx.y, threadIdx.x, q, rpe, hops, khop_ws, Phi, Plo);
}

// ---------------------------------------------------------------------------
// Kernel 3 (r13-PROVEN core + INLINED gate-final scan): per-block wave 0
// reduces the 4 K-slice partials for its (b,h) (identical summation order to
// the removed k_gates_final), runs the proven log-sigmoid/cumsum/prefix-max
// scan, and writes csum/ig/pmax straight into LDS. First __syncthreads()
// covers the dependency. Then split-QK^T w/ causal skip, in-register
// D-weight/normalizer, bf16 Cn, VT-swizzled MFMA PV, in-register LN.
// ---------------------------------------------------------------------------
__global__ __launch_bounds__(256) void k_attn(
    const float* __restrict__ q, const float* __restrict__ k, const float* __restrict__ v,
    const float* __restrict__ lnw, const float* __restrict__ lnb,
    const float* __restrict__ part, const float* __restrict__ igb, const float* __restrict__ fgb,
    const float* __restrict__ khop_ws, float* __restrict__ out)
{
    __shared__ __attribute__((aligned(16))) unsigned short Kspl[2 * 64 * 136];
    __shared__ float csum_s[65];
    __shared__ float ig_s[64];
    __shared__ float pmax_s[64];
    __shared__ float lnw_s[128];
    __shared__ float lnb_s[128];

    const int bid = blockIdx.x;
    const int b = bid >> 3, h = bid & 7;
    const int t = threadIdx.x;
    const int w = t >> 6, l = t & 63, c = l & 15, g = l >> 4;
    const float rs_dh = 0.08838834764831845f;

    unsigned short* Khi = Kspl;
    unsigned short* Klo = Kspl + 64 * 136;

    // ---- INLINED gate-final: wave 0 reduces partials + scans (s = t) ----
    if (t < 64) {
        float sI = 0.f, sF = 0.f;
        #pragma unroll
        for (int ksl = 0; ksl < 4; ++ksl) {
            const float* pp = part + (((size_t)ksl * 256 + b) * 64 + t) * 16;
            sI += pp[h];
            sF += pp[8 + h];
        }
        const float ig = sI + igb[h];
        const float fg = sF + fgb[h];
        const float lf = logsigf(fg);
        float cs = lf;
        #pragma unroll
        for (int d = 1; d < 64; d <<= 1) {
            float o = __shfl_up(cs, (unsigned)d, 64);
            if (t >= d) cs += o;
        }
        float pm = ig - cs;
        #pragma unroll
        for (int d = 1; d < 64; d <<= 1) {
            float o = __shfl_up(pm, (unsigned)d, 64);
            if (t >= d) pm = fmaxf(pm, o);
        }
        csum_s[t + 1] = cs;
        if (t == 0) csum_s[0] = 0.0f;
        ig_s[t] = ig;
        pmax_s[t] = pm;
    }

    // ---- issue V loads into registers early (written to VT after QK^T) ----
    float4 vreg[2][4];
    #pragma unroll
    for (int it = 0; it < 2; ++it) {
        const int u = t + 256 * it;
        const int jp = u >> 4, seg8 = u & 15;
        const float* r0 = v + ((size_t)(b * 64 + 2 * jp)) * 1024 + h * 128 + seg8 * 8;
        vreg[it][0] = *reinterpret_cast<const float4*>(r0);
        vreg[it][1] = *reinterpret_cast<const float4*>(r0 + 4);
        vreg[it][2] = *reinterpret_cast<const float4*>(r0 + 1024);
        vreg[it][3] = *reinterpret_cast<const float4*>(r0 + 1028);
    }

    // ---- khop lane-exact into registers (causal tiles n<=w only) ----
    float kh[4][4];
    {
        const float* khb = khop_ws + ((size_t)(b * NHH + h) * SS) * SS;
        #pragma unroll
        for (int n = 0; n < 4; ++n) {
            if (n > w) continue;
            #pragma unroll
            for (int reg = 0; reg < 4; ++reg) {
                const int i = 16 * w + 4 * g + reg;
                kh[n][reg] = khb[(size_t)i * SS + 16 * n + c];
            }
        }
    }

    // ---- stage K as hi/lo split bf16 (scaled by 1/sqrt(DH) BEFORE split) ----
    #pragma unroll
    for (int it = 0; it < 2; ++it) {
        const int u = t + 256 * it;
        const int row = u >> 3, seg = u & 7;
        const float* kp = k + ((size_t)(b * 64 + row)) * 1024 + h * 128;
        #pragma unroll
        for (int e = 0; e < 2; ++e) {
            const int col = e * 64 + seg * 8;
            const float4 ya = *reinterpret_cast<const float4*>(kp + col);
            const float4 yb = *reinterpret_cast<const float4*>(kp + col + 4);
            unsigned* dh = reinterpret_cast<unsigned*>(&Khi[row * 136 + col]);
            unsigned* dl = reinterpret_cast<unsigned*>(&Klo[row * 136 + col]);
            split2(ya.x * rs_dh, ya.y * rs_dh, dh[0], dl[0]);
            split2(ya.z * rs_dh, ya.w * rs_dh, dh[1], dl[1]);
            split2(yb.x * rs_dh, yb.y * rs_dh, dh[2], dl[2]);
            split2(yb.z * rs_dh, yb.w * rs_dh, dh[3], dl[3]);
        }
    }
    if (t < 128) lnw_s[t] = lnw[h * 128 + t];
    else lnb_s[t - 128] = lnb[h * 128 + (t - 128)];

    // ---- Q A-frags from global, split hi/lo in registers ----
    union bfu { unsigned u[4]; bf16x8 v; };
    bfu qhi[4], qlo[4];
    {
        const int qrow = 16 * w + c;
        const float* qbase = q + ((size_t)(b * 64 + qrow)) * 1024 + h * 128 + 8 * g;
        #pragma unroll
        for (int kk = 0; kk < 4; ++kk) {
            const float4 f0 = *reinterpret_cast<const float4*>(qbase + 32 * kk);
            const float4 f1 = *reinterpret_cast<const float4*>(qbase + 32 * kk + 4);
            split2(f0.x, f0.y, qhi[kk].u[0], qlo[kk].u[0]);
            split2(f0.z, f0.w, qhi[kk].u[1], qlo[kk].u[1]);
            split2(f1.x, f1.y, qhi[kk].u[2], qlo[kk].u[2]);
            split2(f1.z, f1.w, qhi[kk].u[3], qlo[kk].u[3]);
        }
    }
    __syncthreads();

    // ---- QK^T via 3-pass split MFMA on causal tiles (n<=w) ----
    f32x4 acc[4];
    #pragma unroll
    for (int n = 0; n < 4; ++n) { acc[n][0]=0.f; acc[n][1]=0.f; acc[n][2]=0.f; acc[n][3]=0.f; }
    #pragma unroll
    for (int kk = 0; kk < 4; ++kk) {
        #pragma unroll
        for (int n = 0; n < 4; ++n) {
            if (n > w) continue;
            const int off = (16 * n + c) * 136 + 32 * kk + 8 * g;
            bf16x8 bhi = *reinterpret_cast<const bf16x8*>(&Khi[off]);
            bf16x8 blo = *reinterpret_cast<const bf16x8*>(&Klo[off]);
            acc[n] = __builtin_amdgcn_mfma_f32_16x16x32_bf16(qhi[kk].v, bhi, acc[n], 0, 0, 0);
            acc[n] = __builtin_amdgcn_mfma_f32_16x16x32_bf16(qlo[kk].v, bhi, acc[n], 0, 0, 0);
            acc[n] = __builtin_amdgcn_mfma_f32_16x16x32_bf16(qhi[kk].v, blo, acc[n], 0, 0, 0);
        }
    }
    __syncthreads();   // Khi/Klo now dead

    // ---- write V^T (bf16, XOR-swizzled) into dead K region ----
    unsigned short* VT = Kspl;
    unsigned short* Cn = Kspl + 128 * 72;
    #pragma unroll
    for (int it = 0; it < 2; ++it) {
        const int u = t + 256 * it;
        const int jp = u >> 4, seg8 = u & 15;
        float v0[8], v1[8];
        v0[0]=vreg[it][0].x; v0[1]=vreg[it][0].y; v0[2]=vreg[it][0].z; v0[3]=vreg[it][0].w;
        v0[4]=vreg[it][1].x; v0[5]=vreg[it][1].y; v0[6]=vreg[it][1].z; v0[7]=vreg[it][1].w;
        v1[0]=vreg[it][2].x; v1[1]=vreg[it][2].y; v1[2]=vreg[it][2].z; v1[3]=vreg[it][2].w;
        v1[4]=vreg[it][3].x; v1[5]=vreg[it][3].y; v1[6]=vreg[it][3].z; v1[7]=vreg[it][3].w;
        #pragma unroll
        for (int m = 0; m < 8; ++m) {
            const int cc = seg8 * 8 + m;
            unsigned byte = (unsigned)(cc * 144 + 4 * jp);
            byte ^= ((cc >> 3) & 7) << 4;
            *reinterpret_cast<unsigned*>(reinterpret_cast<char*>(VT) + byte) = pk2(v0[m], v1[m]);
        }
    }

    // ---- D-weight + rowsum + normalizer in fragment registers ----
    {
        float mi[4], rs[4];
        #pragma unroll
        for (int reg = 0; reg < 4; ++reg) {
            const int i = 16 * w + 4 * g + reg;
            mi[reg] = csum_s[i + 1] + pmax_s[i];
            rs[reg] = 0.0f;
        }
        #pragma unroll
        for (int n = 0; n < 4; ++n) {
            if (n > w) continue;
            const int j = 16 * n + c;
            const float cj = csum_s[j + 1], igj = ig_s[j];
            #pragma unroll
            for (int reg = 0; reg < 4; ++reg) {
                const int i = 16 * w + 4 * g + reg;
                float val = 0.0f;
                if (j <= i) {
                    const float sc = acc[n][reg] + kh[n][reg];
                    val = sc * __expf(csum_s[i + 1] - cj + igj - mi[reg]);
                }
                acc[n][reg] = val;
                rs[reg] += val;
            }
        }
        #pragma unroll
        for (int reg = 0; reg < 4; ++reg) {
            float r = rs[reg];
            r += __shfl_xor(r, 1); r += __shfl_xor(r, 2);
            r += __shfl_xor(r, 4); r += __shfl_xor(r, 8);
            const float nrm = fmaxf(fabsf(r), __expf(-mi[reg]));
            const float inv = 1.0f / (nrm + 1e-6f);
            const int i = 16 * w + 4 * g + reg;
            #pragma unroll
            for (int n = 0; n < 4; ++n) {
                const int j = 16 * n + c;
                Cn[i * 72 + j] = f2bh(acc[n][reg] * inv);
            }
        }
    }
    __syncthreads();

    // ---- PV via MFMA ----
    f32x4 hacc[8];
    #pragma unroll
    for (int n = 0; n < 8; ++n) { hacc[n][0]=0.f; hacc[n][1]=0.f; hacc[n][2]=0.f; hacc[n][3]=0.f; }
    #pragma unroll
    for (int ks = 0; ks < 2; ++ks) {
        bf16x8 a = *reinterpret_cast<const bf16x8*>(&Cn[(16 * w + c) * 72 + 32 * ks + 8 * g]);
        #pragma unroll
        for (int n = 0; n < 8; ++n) {
            const int cc = 16 * n + c;
            unsigned byte = (unsigned)(cc * 144 + 64 * ks + 16 * g);
            byte ^= ((cc >> 3) & 7) << 4;
            bf16x8 bv = *reinterpret_cast<const bf16x8*>(reinterpret_cast<const char*>(VT) + byte);
            hacc[n] = __builtin_amdgcn_mfma_f32_16x16x32_bf16(a, bv, hacc[n], 0, 0, 0);
        }
    }

    // ---- fused per-head LayerNorm + output ----
    #pragma unroll
    for (int reg = 0; reg < 4; ++reg) {
        float s1 = 0.f, s2 = 0.f;
        #pragma unroll
        for (int n = 0; n < 8; ++n) { const float x = hacc[n][reg]; s1 += x; s2 = fmaf(x, x, s2); }
        s1 += __shfl_xor(s1, 1); s1 += __shfl_xor(s1, 2);
        s1 += __shfl_xor(s1, 4); s1 += __shfl_xor(s1, 8);
        s2 += __shfl_xor(s2, 1); s2 += __shfl_xor(s2, 2);
        s2 += __shfl_xor(s2, 4); s2 += __shfl_xor(s2, 8);
        const float mu = s1 * (1.0f / 128.0f);
        const float var = s2 * (1.0f / 128.0f) - mu * mu;
        const float rstd = rsqrtf(var + 1e-5f);
        const int io = 16 * w + 4 * g + reg;
        float* op = out + (((size_t)(b * 64 + io)) * 8 + h) * 128;
        #pragma unroll
        for (int n = 0; n < 8; ++n) {
            const int cc = 16 * n + c;
            op[cc] = (hacc[n][reg] - mu) * rstd * (1.0f + lnw_s[cc]) + lnb_s[cc];
        }
    }
}

extern "C" void kernel_launch(void* const* d_in, const int* in_sizes, int n_in,
                              void* d_out, int out_size, void* d_ws, size_t ws_size,
                              hipStream_t stream) {
    const float* q   = (const float*)d_in[0];
    const float* k   = (const float*)d_in[1];
    const float* v   = (const float*)d_in[2];
    const float* igw = (const float*)d_in[3];
    const float* igb = (const float*)d_in[4];
    const float* fgw = (const float*)d_in[5];
    const float* fgb = (const float*)d_in[6];
    const float* rpe = (const float*)d_in[7];
    const float* lnw = (const float*)d_in[8];
    const float* lnb = (const float*)d_in[9];
    const int*  hops = (const int*)d_in[10];
    float* out = (float*)d_out;

    // ws (floats): part[4*256*64*16 = 1.05M] | khop_ws[256*8*64*64 = 8.39M]
    float* part    = (float*)d_ws;
    float* khop_ws = part + 1048576;

    const size_t NEED = (size_t)(1048576 + 8388608) * 4;
    if (ws_size >= NEED) {
        hipLaunchKernelGGL(k_gate_khop, dim3(1536), dim3(256), 0, stream,
                           q, k, v, igw, fgw, rpe, hops, part, khop_ws);
    } else {
        hipLaunchKernelGGL(k_gate_mfma, dim3(1024), dim3(256), 0, stream,
                           q, k, v, igw, fgw, part);
        hipLaunchKernelGGL(k_khop, dim3(SS, NHH), dim3(256), 0, stream,
                           q, rpe, hops, khop_ws);
    }
    hipLaunchKernelGGL(k_attn, dim3(BB * NHH), dim3(256), 0, stream,
                       q, k, v, lnw, lnb, part, igb, fgb, khop_ws, out);
}